// Round 2
// baseline (1797.591 us; speedup 1.0000x reference)
//
#include <hip/hip_runtime.h>
#include <stdint.h>

// ---------------------------------------------------------------------------
// color_counter: 128^3 histogram (count + mask-sum) -> log-ratio filter ->
// per-pixel boolean gather.  Output: bool -> int32 0/1 per pixel.
// ws layout:
//   [0,64)                     : double accum[3] = {S_l, S_f, avg_num}
//   [64, 64+4*nbin)            : uint32 counts[nbin]
//   [.., +4*nbin)              : float  lsum[nbin]
//   [.., +4*nbin)              : float  logr[nbin]
//   [.., +1*nbin)              : uint8  filt[nbin]
//   [aligned, +4*npix)         : uint32 bins[npix]   (if ws_size permits)
// ---------------------------------------------------------------------------

__global__ void hist_kernel(const int4* __restrict__ img4,
                            const float4* __restrict__ mask4,
                            uint32_t* __restrict__ counts,
                            float* __restrict__ lsum,
                            uint4* __restrict__ bins4,
                            int npix4) {
    int t = blockIdx.x * blockDim.x + threadIdx.x;
    if (t >= npix4) return;
    int4 a = img4[3 * t + 0];
    int4 b = img4[3 * t + 1];
    int4 c = img4[3 * t + 2];
    float4 m = mask4[t];
    uint32_t bin0 = ((uint32_t)(a.x >> 1) << 14) | ((uint32_t)(a.y >> 1) << 7) | (uint32_t)(a.z >> 1);
    uint32_t bin1 = ((uint32_t)(a.w >> 1) << 14) | ((uint32_t)(b.x >> 1) << 7) | (uint32_t)(b.y >> 1);
    uint32_t bin2 = ((uint32_t)(b.z >> 1) << 14) | ((uint32_t)(b.w >> 1) << 7) | (uint32_t)(c.x >> 1);
    uint32_t bin3 = ((uint32_t)(c.y >> 1) << 14) | ((uint32_t)(c.z >> 1) << 7) | (uint32_t)(c.w >> 1);
    if (bins4) bins4[t] = make_uint4(bin0, bin1, bin2, bin3);
    atomicAdd(&counts[bin0], 1u);
    atomicAdd(&counts[bin1], 1u);
    atomicAdd(&counts[bin2], 1u);
    atomicAdd(&counts[bin3], 1u);
#if __has_builtin(__builtin_amdgcn_global_atomic_fadd_f32)
    unsafeAtomicAdd(&lsum[bin0], m.x);
    unsafeAtomicAdd(&lsum[bin1], m.y);
    unsafeAtomicAdd(&lsum[bin2], m.z);
    unsafeAtomicAdd(&lsum[bin3], m.w);
#else
    atomicAdd(&lsum[bin0], m.x);
    atomicAdd(&lsum[bin1], m.y);
    atomicAdd(&lsum[bin2], m.z);
    atomicAdd(&lsum[bin3], m.w);
#endif
}

__device__ __forceinline__ void block_reduce_add2(double v0, double v1, double* g0, double* g1) {
    // wave64 butterfly then LDS across 4 waves, one atomic per block per value
    for (int o = 32; o > 0; o >>= 1) {
        v0 += __shfl_down(v0, o, 64);
        v1 += __shfl_down(v1, o, 64);
    }
    __shared__ double s0[4], s1[4];
    int lane = threadIdx.x & 63, wid = threadIdx.x >> 6;
    if (lane == 0) { s0[wid] = v0; s1[wid] = v1; }
    __syncthreads();
    if (threadIdx.x == 0) {
        double t0 = s0[0] + s0[1] + s0[2] + s0[3];
        double t1 = s1[0] + s1[1] + s1[2] + s1[3];
        atomicAdd(g0, t0);
        atomicAdd(g1, t1);
    }
}

__global__ void reduce_lf_kernel(const uint32_t* __restrict__ counts,
                                 const float* __restrict__ lsum,
                                 const float* __restrict__ full_in,
                                 const float* __restrict__ lines_in,
                                 double* __restrict__ accum, int nbin) {
    double sl = 0.0, sf = 0.0;
    for (int i = blockIdx.x * blockDim.x + threadIdx.x; i < nbin; i += gridDim.x * blockDim.x) {
        float f = (float)counts[i] + full_in[i] + 1.0f;
        float l = (lsum[i] + lines_in[i]) + 1e-10f;
        sl += (double)l;
        sf += (double)f;
    }
    block_reduce_add2(sl, sf, &accum[0], &accum[1]);
}

__global__ void logr_kernel(const uint32_t* __restrict__ counts,
                            const float* __restrict__ lsum,
                            const float* __restrict__ full_in,
                            const float* __restrict__ lines_in,
                            const double* __restrict__ accum_in,
                            double* __restrict__ accum_avg,
                            float* __restrict__ logr, int nbin) {
    float Sl = (float)accum_in[0];
    float Sf = (float)accum_in[1];
    double acc = 0.0;
    for (int i = blockIdx.x * blockDim.x + threadIdx.x; i < nbin; i += gridDim.x * blockDim.x) {
        float f = (float)counts[i] + full_in[i] + 1.0f;
        float l = (lsum[i] + lines_in[i]) + 1e-10f;
        float ln = l / Sl;          // fp32, mimics reference normalize
        float fn = f / Sf;
        float lr = logf(ln / fn);   // fp32 divide then log, as reference
        logr[i] = lr;
        float prod = ln * lr;       // fp32 product, as reference
        acc += (double)prod;
    }
    for (int o = 32; o > 0; o >>= 1) acc += __shfl_down(acc, o, 64);
    __shared__ double s[4];
    int lane = threadIdx.x & 63, wid = threadIdx.x >> 6;
    if (lane == 0) s[wid] = acc;
    __syncthreads();
    if (threadIdx.x == 0) atomicAdd(accum_avg, s[0] + s[1] + s[2] + s[3]);
}

__global__ void filt_kernel(const float* __restrict__ logr,
                            const double* __restrict__ accum,
                            uint8_t* __restrict__ filt, int nbin) {
    float avg = (float)accum[2];
    int i = blockIdx.x * blockDim.x + threadIdx.x;
    if (i < nbin) filt[i] = (logr[i] > avg) ? (uint8_t)1 : (uint8_t)0;
}

__global__ void out_kernel_bins(const uint4* __restrict__ bins4,
                                const uint8_t* __restrict__ filt,
                                int4* __restrict__ out4, int npix4) {
    int t = blockIdx.x * blockDim.x + threadIdx.x;
    if (t >= npix4) return;
    uint4 b = bins4[t];
    out4[t] = make_int4(filt[b.x] ? 1 : 0,
                        filt[b.y] ? 1 : 0,
                        filt[b.z] ? 1 : 0,
                        filt[b.w] ? 1 : 0);
}

__global__ void out_kernel_img(const int4* __restrict__ img4,
                               const uint8_t* __restrict__ filt,
                               int4* __restrict__ out4, int npix4) {
    int t = blockIdx.x * blockDim.x + threadIdx.x;
    if (t >= npix4) return;
    int4 a = img4[3 * t + 0];
    int4 b = img4[3 * t + 1];
    int4 c = img4[3 * t + 2];
    uint32_t bin0 = ((uint32_t)(a.x >> 1) << 14) | ((uint32_t)(a.y >> 1) << 7) | (uint32_t)(a.z >> 1);
    uint32_t bin1 = ((uint32_t)(a.w >> 1) << 14) | ((uint32_t)(b.x >> 1) << 7) | (uint32_t)(b.y >> 1);
    uint32_t bin2 = ((uint32_t)(b.z >> 1) << 14) | ((uint32_t)(b.w >> 1) << 7) | (uint32_t)(c.x >> 1);
    uint32_t bin3 = ((uint32_t)(c.y >> 1) << 14) | ((uint32_t)(c.z >> 1) << 7) | (uint32_t)(c.w >> 1);
    out4[t] = make_int4(filt[bin0] ? 1 : 0,
                        filt[bin1] ? 1 : 0,
                        filt[bin2] ? 1 : 0,
                        filt[bin3] ? 1 : 0);
}

extern "C" void kernel_launch(void* const* d_in, const int* in_sizes, int n_in,
                              void* d_out, int out_size, void* d_ws, size_t ws_size,
                              hipStream_t stream) {
    const int*   img      = (const int*)d_in[0];
    const float* mask     = (const float*)d_in[1];
    const float* full_in  = (const float*)d_in[2];
    const float* lines_in = (const float*)d_in[3];
    int* out = (int*)d_out;

    const int npix = in_sizes[1];      // 4096*4096
    const int nbin = in_sizes[2];      // 128^3

    char* ws = (char*)d_ws;
    double*   accum  = (double*)ws;
    uint32_t* counts = (uint32_t*)(ws + 64);
    float*    lsum   = (float*)(ws + 64 + 4ull * nbin);
    float*    logr   = (float*)(ws + 64 + 8ull * nbin);
    uint8_t*  filt   = (uint8_t*)(ws + 64 + 12ull * nbin);
    size_t off_bins  = (64 + 13ull * nbin + 255ull) & ~255ull;
    uint32_t* bins   = nullptr;
    if (ws_size >= off_bins + 4ull * (size_t)npix)
        bins = (uint32_t*)(ws + off_bins);

    // zero accum + counts + lsum (re-poisoned to 0xAA before each timed call)
    hipMemsetAsync(ws, 0, 64 + 8ull * nbin, stream);

    const int npix4 = npix / 4;
    const int BLK = 256;

    hist_kernel<<<(npix4 + BLK - 1) / BLK, BLK, 0, stream>>>(
        (const int4*)img, (const float4*)mask, counts, lsum, (uint4*)bins, npix4);

    reduce_lf_kernel<<<1024, BLK, 0, stream>>>(counts, lsum, full_in, lines_in, accum, nbin);

    logr_kernel<<<1024, BLK, 0, stream>>>(counts, lsum, full_in, lines_in,
                                          accum, &accum[2], logr, nbin);

    filt_kernel<<<(nbin + BLK - 1) / BLK, BLK, 0, stream>>>(logr, accum, filt, nbin);

    if (bins) {
        out_kernel_bins<<<(npix4 + BLK - 1) / BLK, BLK, 0, stream>>>(
            (const uint4*)bins, filt, (int4*)out, npix4);
    } else {
        out_kernel_img<<<(npix4 + BLK - 1) / BLK, BLK, 0, stream>>>(
            (const int4*)img, filt, (int4*)out, npix4);
    }
}

// Round 6
// 1697.840 us; speedup vs baseline: 1.0588x; 1.0588x over previous
//
#include <hip/hip_runtime.h>
#include <stdint.h>

// ---------------------------------------------------------------------------
// color_counter: 128^3 histogram -> log-ratio filter -> per-pixel bool gather.
// Output: bool -> int32 0/1 per pixel.
//
// Round-6: fully DETERMINISTIC, bitwise-numpy lsum.
//   Root cause of round-5 tripwire failure: fp32 add-order nondeterminism in
//   lsum flips threshold-boundary bins (~10%/run). Fix: per-bin contributions
//   are sorted by pixel index and summed sequentially in fp32 — bitwise equal
//   to np.add.at's in-order accumulation, and identical on every launch.
//   All bin-space reductions use fixed-order partials (no float/double
//   atomics anywhere in the deterministic path).
//
// Pipeline (tier A/B):
//   p1_scatter_det : stream pixels; partition per 512-bucket segments the
//                    streams gbin16 (bin&4095) and gpm ((pix<<32)|maskbits);
//                    optional bins[] for the output gather.
//   p2_sort_hist   : per bucket: LDS count/scan/scatter -> per-bin contiguous
//                    runs in srt[]; insertion-sort each run by pix; fp32
//                    sequential sum -> counts[], lsum[].  Zero atomics to HBM.
//   reduce_lf -> final_lf -> logr -> final_avg -> filt -> out   (fixed order)
// Tier C fallback (ws too small): round-2 direct atomics (nondeterministic).
// ---------------------------------------------------------------------------

typedef uint32_t u32x4 __attribute__((ext_vector_type(4)));

#define NBKT      512
#define BKT_SHIFT 12
#define BPB       4096        // bins per bucket
#define CAP       34816       // pairs/bucket: mean 32768 + 11 sigma
#define P1_BLK    512
#define P1_PIXG   1024        // 4-pixel groups per block -> 4096 pixels/block

// ---------------- pass 1: deterministic-content partition ------------------
__global__ __launch_bounds__(P1_BLK) void p1_scatter_det(
    const u32x4* __restrict__ img4, const u32x4* __restrict__ mask4,
    uint32_t* __restrict__ cursor,
    unsigned short* __restrict__ gbin, unsigned long long* __restrict__ gpm,
    u32x4* __restrict__ bins4)
{
    __shared__ uint32_t s_cnt[NBKT];
    __shared__ uint32_t s_start[NBKT];
    __shared__ int      s_adj[NBKT];
    __shared__ uint32_t s_wsum[P1_BLK / 64];
    __shared__ uint32_t s_bin[P1_PIXG * 4];              // 16 KB
    __shared__ unsigned long long s_pm[P1_PIXG * 4];     // 32 KB

    const int tid = threadIdx.x;
    s_cnt[tid] = 0;                                      // P1_BLK == NBKT
    __syncthreads();

    const int g0 = blockIdx.x * P1_PIXG;
    uint32_t bin[8], rk[8];
    unsigned long long pm[8];

    #pragma unroll
    for (int k = 0; k < 2; ++k) {
        int g = g0 + tid + k * P1_BLK;                   // 4-pixel group id
        u32x4 a = __builtin_nontemporal_load(&img4[3 * g + 0]);
        u32x4 b = __builtin_nontemporal_load(&img4[3 * g + 1]);
        u32x4 c = __builtin_nontemporal_load(&img4[3 * g + 2]);
        u32x4 m = __builtin_nontemporal_load(&mask4[g]);
        uint32_t b0 = ((a.x >> 1) << 14) | ((a.y >> 1) << 7) | (a.z >> 1);
        uint32_t b1 = ((a.w >> 1) << 14) | ((b.x >> 1) << 7) | (b.y >> 1);
        uint32_t b2 = ((b.z >> 1) << 14) | ((b.w >> 1) << 7) | (c.x >> 1);
        uint32_t b3 = ((c.y >> 1) << 14) | ((c.z >> 1) << 7) | (c.w >> 1);
        if (bins4) {
            u32x4 bv = {b0, b1, b2, b3};
            __builtin_nontemporal_store(bv, &bins4[g]);
        }
        unsigned long long p0 = (unsigned long long)(4u * (uint32_t)g);
        bin[4*k+0] = b0; pm[4*k+0] = ((p0 + 0) << 32) | m.x; rk[4*k+0] = atomicAdd(&s_cnt[b0 >> BKT_SHIFT], 1u);
        bin[4*k+1] = b1; pm[4*k+1] = ((p0 + 1) << 32) | m.y; rk[4*k+1] = atomicAdd(&s_cnt[b1 >> BKT_SHIFT], 1u);
        bin[4*k+2] = b2; pm[4*k+2] = ((p0 + 2) << 32) | m.z; rk[4*k+2] = atomicAdd(&s_cnt[b2 >> BKT_SHIFT], 1u);
        bin[4*k+3] = b3; pm[4*k+3] = ((p0 + 3) << 32) | m.w; rk[4*k+3] = atomicAdd(&s_cnt[b3 >> BKT_SHIFT], 1u);
    }
    __syncthreads();

    // exclusive prefix sum of s_cnt -> s_start
    uint32_t v = s_cnt[tid];
    uint32_t inc = v;
    #pragma unroll
    for (int o = 1; o < 64; o <<= 1) {
        uint32_t n = __shfl_up(inc, o, 64);
        if ((tid & 63) >= o) inc += n;
    }
    if ((tid & 63) == 63) s_wsum[tid >> 6] = inc;
    __syncthreads();
    if (tid == 0) {
        uint32_t run = 0;
        #pragma unroll
        for (int w = 0; w < P1_BLK / 64; ++w) { uint32_t t = s_wsum[w]; s_wsum[w] = run; run += t; }
    }
    __syncthreads();
    uint32_t start = inc - v + s_wsum[tid >> 6];
    s_start[tid] = start;
    uint32_t gb = v ? atomicAdd(&cursor[tid], v) : 0u;
    s_adj[tid] = (int)gb - (int)start;
    __syncthreads();

    // bucket-sorted LDS staging
    #pragma unroll
    for (int k = 0; k < 8; ++k) {
        uint32_t slot = s_start[bin[k] >> BKT_SHIFT] + rk[k];
        s_bin[slot] = bin[k];
        s_pm[slot]  = pm[k];
    }
    __syncthreads();

    // coalesced run write-out: two streams
    for (int i = tid; i < P1_PIXG * 4; i += P1_BLK) {
        uint32_t bf = s_bin[i];
        uint32_t bk = bf >> BKT_SHIFT;
        uint32_t pos = (uint32_t)(s_adj[bk] + i);
        if (pos < CAP) {
            size_t idx = (size_t)bk * CAP + pos;
            __builtin_nontemporal_store((unsigned short)(bf & (BPB - 1)), &gbin[idx]);
            __builtin_nontemporal_store(s_pm[i], &gpm[idx]);
        }
    }
}

// ---------------- pass 2: per-bucket sort + sequential fp32 sums -----------
__global__ __launch_bounds__(1024) void p2_sort_hist(
    const unsigned short* __restrict__ gbin,
    const unsigned long long* __restrict__ gpm,
    const uint32_t* __restrict__ cursor,
    unsigned long long* __restrict__ srt,
    uint32_t* __restrict__ counts, float* __restrict__ lsum)
{
    __shared__ uint32_t s_cnt[BPB];     // 16 KB
    __shared__ uint32_t s_start[BPB];   // 16 KB
    __shared__ uint32_t s_fill[BPB];    // 16 KB
    __shared__ uint32_t s_wt[16];

    const int tid = threadIdx.x;
    const int b = blockIdx.x;
    for (int j = tid; j < BPB; j += 1024) s_cnt[j] = 0u;
    __syncthreads();

    uint32_t n = cursor[b];
    if (n > CAP) n = CAP;
    const size_t base = (size_t)b * CAP;

    for (uint32_t i = tid; i < n; i += 1024)
        atomicAdd(&s_cnt[gbin[base + i]], 1u);
    __syncthreads();

    // exclusive scan of s_cnt (4096) with 1024 threads x 4
    const int j0 = tid * 4;
    uint32_t a0 = s_cnt[j0+0], a1 = s_cnt[j0+1], a2 = s_cnt[j0+2], a3 = s_cnt[j0+3];
    uint32_t s = a0 + a1 + a2 + a3;
    uint32_t inc = s;
    #pragma unroll
    for (int o = 1; o < 64; o <<= 1) {
        uint32_t t = __shfl_up(inc, o, 64);
        if ((tid & 63) >= o) inc += t;
    }
    if ((tid & 63) == 63) s_wt[tid >> 6] = inc;
    __syncthreads();
    if (tid == 0) {
        uint32_t run = 0;
        #pragma unroll
        for (int w = 0; w < 16; ++w) { uint32_t t = s_wt[w]; s_wt[w] = run; run += t; }
    }
    __syncthreads();
    uint32_t ex = s_wt[tid >> 6] + (inc - s);
    uint32_t e0 = ex, e1 = ex + a0, e2 = e1 + a1, e3 = e2 + a2;
    s_start[j0+0] = e0; s_start[j0+1] = e1; s_start[j0+2] = e2; s_start[j0+3] = e3;
    s_fill[j0+0] = 0u;  s_fill[j0+1] = 0u;  s_fill[j0+2] = 0u;  s_fill[j0+3] = 0u;
    __syncthreads();

    // scatter pairs into per-bin contiguous runs (order within run arbitrary)
    for (uint32_t i = tid; i < n; i += 1024) {
        uint32_t lo = gbin[base + i];
        unsigned long long pmv = __builtin_nontemporal_load(&gpm[base + i]);
        uint32_t slot = s_start[lo] + atomicAdd(&s_fill[lo], 1u);
        srt[base + slot] = pmv;
    }
    __threadfence_block();
    __syncthreads();

    // per-bin: sort by pixel index (u64 high bits), sequential fp32 sum
    uint32_t cs[4] = {a0, a1, a2, a3};
    uint32_t ss[4] = {e0, e1, e2, e3};
    #pragma unroll
    for (int t = 0; t < 4; ++t) {
        uint32_t c = cs[t];
        unsigned long long* arr = srt + base + ss[t];
        for (uint32_t x = 1; x < c; ++x) {           // insertion sort (runs ~8)
            unsigned long long v = arr[x];
            int y = (int)x - 1;
            while (y >= 0 && arr[y] > v) { arr[y+1] = arr[y]; --y; }
            arr[y+1] = v;
        }
        float sum = 0.0f;
        for (uint32_t x = 0; x < c; ++x)
            sum += __uint_as_float((uint32_t)arr[x]);  // pixel-index order
        size_t gbidx = (size_t)b * BPB + (size_t)(j0 + t);
        counts[gbidx] = c;
        lsum[gbidx]   = sum;
    }
}

// ---------------- tier-C fallback: direct atomics (round-2) ----------------
__global__ void hist_direct_kernel(const u32x4* __restrict__ img4,
                                   const u32x4* __restrict__ mask4,
                                   uint32_t* __restrict__ counts,
                                   float* __restrict__ lsum, int npix4) {
    int t = blockIdx.x * blockDim.x + threadIdx.x;
    if (t >= npix4) return;
    u32x4 a = img4[3 * t + 0];
    u32x4 b = img4[3 * t + 1];
    u32x4 c = img4[3 * t + 2];
    u32x4 m = mask4[t];
    uint32_t b0 = ((a.x >> 1) << 14) | ((a.y >> 1) << 7) | (a.z >> 1);
    uint32_t b1 = ((a.w >> 1) << 14) | ((b.x >> 1) << 7) | (b.y >> 1);
    uint32_t b2 = ((b.z >> 1) << 14) | ((b.w >> 1) << 7) | (c.x >> 1);
    uint32_t b3 = ((c.y >> 1) << 14) | ((c.z >> 1) << 7) | (c.w >> 1);
    atomicAdd(&counts[b0], 1u);
    atomicAdd(&counts[b1], 1u);
    atomicAdd(&counts[b2], 1u);
    atomicAdd(&counts[b3], 1u);
    unsafeAtomicAdd(&lsum[b0], __uint_as_float(m.x));
    unsafeAtomicAdd(&lsum[b1], __uint_as_float(m.y));
    unsafeAtomicAdd(&lsum[b2], __uint_as_float(m.z));
    unsafeAtomicAdd(&lsum[b3], __uint_as_float(m.w));
}

// ---------------- deterministic bin-space pipeline -------------------------
__global__ __launch_bounds__(256) void reduce_lf_kernel(
    const uint32_t* __restrict__ counts, const float* __restrict__ lsum,
    const float* __restrict__ full_in, const float* __restrict__ lines_in,
    double* __restrict__ part_lf, int nbin) {
    double sl = 0.0, sf = 0.0;
    for (int i = blockIdx.x * 256 + threadIdx.x; i < nbin; i += 256 * 256) {
        float f = (float)counts[i] + full_in[i] + 1.0f;
        float l = (lsum[i] + lines_in[i]) + 1e-10f;
        sl += (double)l;
        sf += (double)f;
    }
    for (int o = 32; o > 0; o >>= 1) {
        sl += __shfl_down(sl, o, 64);
        sf += __shfl_down(sf, o, 64);
    }
    __shared__ double s0[4], s1[4];
    int lane = threadIdx.x & 63, wid = threadIdx.x >> 6;
    if (lane == 0) { s0[wid] = sl; s1[wid] = sf; }
    __syncthreads();
    if (threadIdx.x == 0) {
        part_lf[blockIdx.x * 2 + 0] = s0[0] + s0[1] + s0[2] + s0[3];
        part_lf[blockIdx.x * 2 + 1] = s1[0] + s1[1] + s1[2] + s1[3];
    }
}

__global__ void final_lf_kernel(const double* __restrict__ part_lf,
                                double* __restrict__ accum) {
    if (threadIdx.x == 0 && blockIdx.x == 0) {
        double sl = 0.0, sf = 0.0;
        for (int i = 0; i < 256; ++i) { sl += part_lf[2*i]; sf += part_lf[2*i+1]; }
        accum[0] = sl;
        accum[1] = sf;
    }
}

__global__ __launch_bounds__(256) void logr_kernel(
    const uint32_t* __restrict__ counts, const float* __restrict__ lsum,
    const float* __restrict__ full_in, const float* __restrict__ lines_in,
    const double* __restrict__ accum, double* __restrict__ part_avg,
    float* __restrict__ logr, int nbin) {
    float Sl = (float)accum[0];
    float Sf = (float)accum[1];
    double acc = 0.0;
    for (int i = blockIdx.x * 256 + threadIdx.x; i < nbin; i += 256 * 256) {
        float f = (float)counts[i] + full_in[i] + 1.0f;
        float l = (lsum[i] + lines_in[i]) + 1e-10f;
        float ln = l / Sl;
        float fn = f / Sf;
        float lr = logf(ln / fn);
        logr[i] = lr;
        acc += (double)(ln * lr);
    }
    for (int o = 32; o > 0; o >>= 1) acc += __shfl_down(acc, o, 64);
    __shared__ double s[4];
    int lane = threadIdx.x & 63, wid = threadIdx.x >> 6;
    if (lane == 0) s[wid] = acc;
    __syncthreads();
    if (threadIdx.x == 0) part_avg[blockIdx.x] = s[0] + s[1] + s[2] + s[3];
}

__global__ void final_avg_kernel(const double* __restrict__ part_avg,
                                 double* __restrict__ accum) {
    if (threadIdx.x == 0 && blockIdx.x == 0) {
        double a = 0.0;
        for (int i = 0; i < 256; ++i) a += part_avg[i];
        accum[2] = a;
    }
}

__global__ void filt_kernel(const float* __restrict__ logr,
                            const double* __restrict__ accum,
                            uint8_t* __restrict__ filt, int nbin) {
    float avg = (float)accum[2];
    int i = blockIdx.x * blockDim.x + threadIdx.x;
    if (i < nbin) filt[i] = (logr[i] > avg) ? (uint8_t)1 : (uint8_t)0;
}

__global__ void out_kernel_bins(const u32x4* __restrict__ bins4,
                                const uint8_t* __restrict__ filt,
                                u32x4* __restrict__ out4, int npix4) {
    int t = blockIdx.x * blockDim.x + threadIdx.x;
    if (t >= npix4) return;
    u32x4 b = __builtin_nontemporal_load(&bins4[t]);
    u32x4 o = {filt[b.x] ? 1u : 0u, filt[b.y] ? 1u : 0u,
               filt[b.z] ? 1u : 0u, filt[b.w] ? 1u : 0u};
    __builtin_nontemporal_store(o, &out4[t]);
}

__global__ void out_kernel_img(const u32x4* __restrict__ img4,
                               const uint8_t* __restrict__ filt,
                               u32x4* __restrict__ out4, int npix4) {
    int t = blockIdx.x * blockDim.x + threadIdx.x;
    if (t >= npix4) return;
    u32x4 a = __builtin_nontemporal_load(&img4[3 * t + 0]);
    u32x4 b = __builtin_nontemporal_load(&img4[3 * t + 1]);
    u32x4 c = __builtin_nontemporal_load(&img4[3 * t + 2]);
    uint32_t b0 = ((a.x >> 1) << 14) | ((a.y >> 1) << 7) | (a.z >> 1);
    uint32_t b1 = ((a.w >> 1) << 14) | ((b.x >> 1) << 7) | (b.y >> 1);
    uint32_t b2 = ((b.z >> 1) << 14) | ((b.w >> 1) << 7) | (c.x >> 1);
    uint32_t b3 = ((c.y >> 1) << 14) | ((c.z >> 1) << 7) | (c.w >> 1);
    u32x4 o = {filt[b0] ? 1u : 0u, filt[b1] ? 1u : 0u,
               filt[b2] ? 1u : 0u, filt[b3] ? 1u : 0u};
    __builtin_nontemporal_store(o, &out4[t]);
}

extern "C" void kernel_launch(void* const* d_in, const int* in_sizes, int n_in,
                              void* d_out, int out_size, void* d_ws, size_t ws_size,
                              hipStream_t stream) {
    const int*   img      = (const int*)d_in[0];
    const float* mask     = (const float*)d_in[1];
    const float* full_in  = (const float*)d_in[2];
    const float* lines_in = (const float*)d_in[3];

    const int npix  = in_sizes[1];     // 4096*4096
    const int nbin  = in_sizes[2];     // 128^3
    const int npix4 = npix / 4;

    char* ws = (char*)d_ws;
    const size_t off_cursor = 64;
    const size_t off_plf    = off_cursor + 4ull * NBKT;            // 2112
    const size_t off_pavg   = off_plf + 256ull * 2 * 8;            // +4096
    const size_t off_hdrend = (off_pavg + 256ull * 8 + 255ull) & ~255ull;  // 8448
    const size_t off_counts = off_hdrend;
    const size_t off_lsum   = off_counts + 4ull * nbin;
    const size_t off_logr   = off_lsum + 4ull * nbin;
    const size_t off_filt   = off_logr + 4ull * nbin;
    const size_t off_gbin   = (off_filt + (size_t)nbin + 255ull) & ~255ull;
    const size_t off_gpm    = (off_gbin + 2ull * NBKT * CAP + 255ull) & ~255ull;
    const size_t off_srt    = off_gpm + 8ull * NBKT * CAP;
    const size_t need_B     = off_srt + 8ull * NBKT * CAP;
    const size_t off_bins   = need_B;
    const size_t need_A     = off_bins + 4ull * (size_t)npix;

    double*   accum  = (double*)ws;
    uint32_t* cursor = (uint32_t*)(ws + off_cursor);
    double*   plf    = (double*)(ws + off_plf);
    double*   pavg   = (double*)(ws + off_pavg);
    uint32_t* counts = (uint32_t*)(ws + off_counts);
    float*    lsum   = (float*)(ws + off_lsum);
    float*    logr   = (float*)(ws + off_logr);
    uint8_t*  filt   = (uint8_t*)(ws + off_filt);
    unsigned short*     gbin = (unsigned short*)(ws + off_gbin);
    unsigned long long* gpm  = (unsigned long long*)(ws + off_gpm);
    unsigned long long* srt  = (unsigned long long*)(ws + off_srt);
    uint32_t* bins = (uint32_t*)(ws + off_bins);

    const bool shape_ok = (nbin == NBKT * BPB) && (npix % (P1_PIXG * 4) == 0);
    const bool tierA = shape_ok && ws_size >= need_A;
    const bool tierB = shape_ok && ws_size >= need_B;
    const int BLK = 256;

    if (tierB) {
        hipMemsetAsync(ws, 0, off_hdrend, stream);   // accum+cursor+partials
        p1_scatter_det<<<npix / (P1_PIXG * 4), P1_BLK, 0, stream>>>(
            (const u32x4*)img, (const u32x4*)mask, cursor, gbin, gpm,
            tierA ? (u32x4*)bins : nullptr);
        p2_sort_hist<<<NBKT, 1024, 0, stream>>>(gbin, gpm, cursor, srt, counts, lsum);
    } else {
        hipMemsetAsync(ws, 0, off_logr, stream);     // + counts + lsum
        hist_direct_kernel<<<(npix4 + BLK - 1) / BLK, BLK, 0, stream>>>(
            (const u32x4*)img, (const u32x4*)mask, counts, lsum, npix4);
    }

    reduce_lf_kernel<<<256, 256, 0, stream>>>(counts, lsum, full_in, lines_in, plf, nbin);
    final_lf_kernel<<<1, 64, 0, stream>>>(plf, accum);
    logr_kernel<<<256, 256, 0, stream>>>(counts, lsum, full_in, lines_in,
                                         accum, pavg, logr, nbin);
    final_avg_kernel<<<1, 64, 0, stream>>>(pavg, accum);
    filt_kernel<<<(nbin + BLK - 1) / BLK, BLK, 0, stream>>>(logr, accum, filt, nbin);

    if (tierA) {
        out_kernel_bins<<<(npix4 + BLK - 1) / BLK, BLK, 0, stream>>>(
            (const u32x4*)bins, filt, (u32x4*)d_out, npix4);
    } else {
        out_kernel_img<<<(npix4 + BLK - 1) / BLK, BLK, 0, stream>>>(
            (const u32x4*)img, filt, (u32x4*)d_out, npix4);
    }
}

// Round 7
// 973.234 us; speedup vs baseline: 1.8470x; 1.7445x over previous
//
#include <hip/hip_runtime.h>
#include <stdint.h>

// ---------------------------------------------------------------------------
// color_counter: 128^3 histogram -> log-ratio filter -> per-pixel bool gather.
// Output: bool -> int32 0/1 per pixel.
//
// Round-7: kill p2_sort_hist's global RMW amplification (989us, WRITE 1.35GB
// for ~160MB payload: random 8B scatter + global insertion sort = 64B
// partial-line RMW per element). Replacement, all fine-grained work in LDS:
//   p1  (unchanged): 512-bucket partition, coalesced runs (~32 pairs).
//   p15 (new): per bucket, stream segment in 4096-entry chunks; LDS-stage and
//       sub-partition into 8 x 512-bin sub-segments; block-local cursors
//       (deterministic, no global atomics); coalesced ~512-entry runs out.
//   p2b (new): per 4608-entry sub-segment: LDS count/scan/scatter (37KB),
//       per-thread bin insertion-sort in LDS, sequential fp32 sum in pixel
//       order -> bitwise-numpy lsum, launch-invariant. Writes only
//       counts/lsum (coalesced).
// Tiers: new path needs ~395MB ws; fallback = exact round-6 pipeline
// (srt-based, known passing, ~348MB); last resort direct atomics.
// ---------------------------------------------------------------------------

typedef uint32_t u32x4 __attribute__((ext_vector_type(4)));

#define NBKT      512
#define BKT_SHIFT 12
#define BPB       4096        // bins per bucket
#define CAP       34816       // pairs/bucket: mean 32768 + 11 sigma
#define P1_BLK    512
#define P1_PIXG   1024        // 4-pixel groups per block -> 4096 pixels/block
#define NSUB      8           // sub-buckets per bucket (512 bins each)
#define SUBCAP    4608        // entries per sub-segment: mean 4096 + 8 sigma

// ---------------- pass 1: bucket partition (unchanged from round 6) --------
__global__ __launch_bounds__(P1_BLK) void p1_scatter_det(
    const u32x4* __restrict__ img4, const u32x4* __restrict__ mask4,
    uint32_t* __restrict__ cursor,
    unsigned short* __restrict__ gbin, unsigned long long* __restrict__ gpm)
{
    __shared__ uint32_t s_cnt[NBKT];
    __shared__ uint32_t s_start[NBKT];
    __shared__ int      s_adj[NBKT];
    __shared__ uint32_t s_wsum[P1_BLK / 64];
    __shared__ uint32_t s_bin[P1_PIXG * 4];
    __shared__ unsigned long long s_pm[P1_PIXG * 4];

    const int tid = threadIdx.x;
    s_cnt[tid] = 0;
    __syncthreads();

    const int g0 = blockIdx.x * P1_PIXG;
    uint32_t bin[8], rk[8];
    unsigned long long pm[8];

    #pragma unroll
    for (int k = 0; k < 2; ++k) {
        int g = g0 + tid + k * P1_BLK;
        u32x4 a = __builtin_nontemporal_load(&img4[3 * g + 0]);
        u32x4 b = __builtin_nontemporal_load(&img4[3 * g + 1]);
        u32x4 c = __builtin_nontemporal_load(&img4[3 * g + 2]);
        u32x4 m = __builtin_nontemporal_load(&mask4[g]);
        uint32_t b0 = ((a.x >> 1) << 14) | ((a.y >> 1) << 7) | (a.z >> 1);
        uint32_t b1 = ((a.w >> 1) << 14) | ((b.x >> 1) << 7) | (b.y >> 1);
        uint32_t b2 = ((b.z >> 1) << 14) | ((b.w >> 1) << 7) | (c.x >> 1);
        uint32_t b3 = ((c.y >> 1) << 14) | ((c.z >> 1) << 7) | (c.w >> 1);
        unsigned long long p0 = (unsigned long long)(4u * (uint32_t)g);
        bin[4*k+0] = b0; pm[4*k+0] = ((p0 + 0) << 32) | m.x; rk[4*k+0] = atomicAdd(&s_cnt[b0 >> BKT_SHIFT], 1u);
        bin[4*k+1] = b1; pm[4*k+1] = ((p0 + 1) << 32) | m.y; rk[4*k+1] = atomicAdd(&s_cnt[b1 >> BKT_SHIFT], 1u);
        bin[4*k+2] = b2; pm[4*k+2] = ((p0 + 2) << 32) | m.z; rk[4*k+2] = atomicAdd(&s_cnt[b2 >> BKT_SHIFT], 1u);
        bin[4*k+3] = b3; pm[4*k+3] = ((p0 + 3) << 32) | m.w; rk[4*k+3] = atomicAdd(&s_cnt[b3 >> BKT_SHIFT], 1u);
    }
    __syncthreads();

    uint32_t v = s_cnt[tid];
    uint32_t inc = v;
    #pragma unroll
    for (int o = 1; o < 64; o <<= 1) {
        uint32_t n = __shfl_up(inc, o, 64);
        if ((tid & 63) >= o) inc += n;
    }
    if ((tid & 63) == 63) s_wsum[tid >> 6] = inc;
    __syncthreads();
    if (tid == 0) {
        uint32_t run = 0;
        #pragma unroll
        for (int w = 0; w < P1_BLK / 64; ++w) { uint32_t t = s_wsum[w]; s_wsum[w] = run; run += t; }
    }
    __syncthreads();
    uint32_t start = inc - v + s_wsum[tid >> 6];
    s_start[tid] = start;
    uint32_t gb = v ? atomicAdd(&cursor[tid], v) : 0u;
    s_adj[tid] = (int)gb - (int)start;
    __syncthreads();

    #pragma unroll
    for (int k = 0; k < 8; ++k) {
        uint32_t slot = s_start[bin[k] >> BKT_SHIFT] + rk[k];
        s_bin[slot] = bin[k];
        s_pm[slot]  = pm[k];
    }
    __syncthreads();

    for (int i = tid; i < P1_PIXG * 4; i += P1_BLK) {
        uint32_t bf = s_bin[i];
        uint32_t bk = bf >> BKT_SHIFT;
        uint32_t pos = (uint32_t)(s_adj[bk] + i);
        if (pos < CAP) {
            size_t idx = (size_t)bk * CAP + pos;
            __builtin_nontemporal_store((unsigned short)(bf & (BPB - 1)), &gbin[idx]);
            __builtin_nontemporal_store(s_pm[i], &gpm[idx]);
        }
    }
}

// ---------------- pass 1.5: sub-partition each bucket into 8 (coalesced) ---
__global__ __launch_bounds__(1024) void p15_subpart(
    const unsigned short* __restrict__ gbin,
    const unsigned long long* __restrict__ gpm,
    const uint32_t* __restrict__ cursor,
    unsigned short* __restrict__ gb2,
    unsigned long long* __restrict__ gpm2,
    uint32_t* __restrict__ cnt2)
{
    __shared__ uint32_t s_c[NSUB], s_st[NSUB + 1], s_of[NSUB];
    __shared__ unsigned short s_sb[4096];             // 8 KB
    __shared__ unsigned long long s_sp[4096];         // 32 KB

    const int tid = threadIdx.x;
    const int b = blockIdx.x;
    uint32_t n = cursor[b];
    if (n > CAP) n = CAP;
    const size_t base = (size_t)b * CAP;

    if (tid < NSUB) s_of[tid] = 0u;
    __syncthreads();

    for (uint32_t c0 = 0; c0 < n; c0 += 4096) {
        const uint32_t cn = (n - c0 < 4096u) ? (n - c0) : 4096u;
        if (tid < NSUB) s_c[tid] = 0u;
        __syncthreads();

        uint32_t myb[4]; unsigned long long myp[4]; uint32_t myr[4];
        #pragma unroll
        for (int k = 0; k < 4; ++k) {
            uint32_t i = (uint32_t)tid + k * 1024u;
            if (i < cn) {
                uint32_t bl = gbin[base + c0 + i];
                myp[k] = __builtin_nontemporal_load(&gpm[base + c0 + i]);
                myr[k] = atomicAdd(&s_c[bl >> 9], 1u);
                myb[k] = bl;
            } else myb[k] = 0xFFFFFFFFu;
        }
        __syncthreads();
        if (tid == 0) {
            uint32_t run = 0;
            #pragma unroll
            for (int r = 0; r < NSUB; ++r) { s_st[r] = run; run += s_c[r]; }
            s_st[NSUB] = run;
        }
        __syncthreads();
        #pragma unroll
        for (int k = 0; k < 4; ++k) {
            if (myb[k] != 0xFFFFFFFFu) {
                uint32_t slot = s_st[myb[k] >> 9] + myr[k];
                s_sb[slot] = (unsigned short)myb[k];
                s_sp[slot] = myp[k];
            }
        }
        __syncthreads();

        // coalesced write-out: sub-runs of mean ~512 entries
        for (uint32_t i = tid; i < cn; i += 1024) {
            uint32_t bl = s_sb[i];
            uint32_t r = bl >> 9;
            uint32_t pos = s_of[r] + (i - s_st[r]);
            if (pos < SUBCAP) {
                size_t d = ((size_t)b * NSUB + r) * SUBCAP + pos;
                __builtin_nontemporal_store((unsigned short)bl, &gb2[d]);
                __builtin_nontemporal_store(s_sp[i], &gpm2[d]);
            }
        }
        __syncthreads();
        if (tid < NSUB) s_of[tid] += s_c[tid];
        __syncthreads();
    }
    if (tid < NSUB) {
        uint32_t c = s_of[tid];
        cnt2[b * NSUB + tid] = (c > SUBCAP) ? SUBCAP : c;
    }
}

// ---------------- pass 2: per-sub-segment LDS sort + sequential sums -------
__global__ __launch_bounds__(512) void p2_binhist(
    const unsigned short* __restrict__ gb2,
    const unsigned long long* __restrict__ gpm2,
    const uint32_t* __restrict__ cnt2,
    uint32_t* __restrict__ counts, float* __restrict__ lsum)
{
    __shared__ uint32_t s_cnt[512], s_start[512], s_fill[512];
    __shared__ uint32_t s_wt[8];
    __shared__ unsigned long long s_srt[SUBCAP];      // 36 KB

    const int tid = threadIdx.x;
    const int s = blockIdx.x;
    const uint32_t n = cnt2[s];
    const size_t base = (size_t)s * SUBCAP;

    s_cnt[tid] = 0u;
    s_fill[tid] = 0u;
    __syncthreads();

    for (uint32_t i = tid; i < n; i += 512)
        atomicAdd(&s_cnt[gb2[base + i] & 511u], 1u);
    __syncthreads();

    uint32_t v = s_cnt[tid], inc = v;
    #pragma unroll
    for (int o = 1; o < 64; o <<= 1) {
        uint32_t t = __shfl_up(inc, o, 64);
        if ((tid & 63) >= o) inc += t;
    }
    if ((tid & 63) == 63) s_wt[tid >> 6] = inc;
    __syncthreads();
    if (tid == 0) {
        uint32_t run = 0;
        #pragma unroll
        for (int w = 0; w < 8; ++w) { uint32_t t = s_wt[w]; s_wt[w] = run; run += t; }
    }
    __syncthreads();
    const uint32_t st = s_wt[tid >> 6] + inc - v;
    s_start[tid] = st;
    __syncthreads();

    for (uint32_t i = tid; i < n; i += 512) {
        uint32_t lo = gb2[base + i] & 511u;
        unsigned long long pv = __builtin_nontemporal_load(&gpm2[base + i]);
        uint32_t slot = s_start[lo] + atomicAdd(&s_fill[lo], 1u);
        s_srt[slot] = pv;
    }
    __syncthreads();

    // thread tid owns bin tid: insertion-sort its LDS run by pix, sum in order
    const uint32_t c = v;
    for (uint32_t x = 1; x < c; ++x) {
        unsigned long long val = s_srt[st + x];
        int y = (int)x - 1;
        while (y >= 0 && s_srt[st + y] > val) { s_srt[st + y + 1] = s_srt[st + y]; --y; }
        s_srt[st + y + 1] = val;
    }
    float sum = 0.0f;
    for (uint32_t x = 0; x < c; ++x)
        sum += __uint_as_float((uint32_t)s_srt[st + x]);
    counts[(size_t)s * 512 + tid] = c;
    lsum[(size_t)s * 512 + tid]   = sum;
}

// ---------------- mid-tier fallback: round-6 p2_sort_hist ------------------
__global__ __launch_bounds__(1024) void p2_sort_hist(
    const unsigned short* __restrict__ gbin,
    const unsigned long long* __restrict__ gpm,
    const uint32_t* __restrict__ cursor,
    unsigned long long* __restrict__ srt,
    uint32_t* __restrict__ counts, float* __restrict__ lsum)
{
    __shared__ uint32_t s_cnt[BPB];
    __shared__ uint32_t s_start[BPB];
    __shared__ uint32_t s_fill[BPB];
    __shared__ uint32_t s_wt[16];

    const int tid = threadIdx.x;
    const int b = blockIdx.x;
    for (int j = tid; j < BPB; j += 1024) s_cnt[j] = 0u;
    __syncthreads();

    uint32_t n = cursor[b];
    if (n > CAP) n = CAP;
    const size_t base = (size_t)b * CAP;

    for (uint32_t i = tid; i < n; i += 1024)
        atomicAdd(&s_cnt[gbin[base + i]], 1u);
    __syncthreads();

    const int j0 = tid * 4;
    uint32_t a0 = s_cnt[j0+0], a1 = s_cnt[j0+1], a2 = s_cnt[j0+2], a3 = s_cnt[j0+3];
    uint32_t s = a0 + a1 + a2 + a3;
    uint32_t inc = s;
    #pragma unroll
    for (int o = 1; o < 64; o <<= 1) {
        uint32_t t = __shfl_up(inc, o, 64);
        if ((tid & 63) >= o) inc += t;
    }
    if ((tid & 63) == 63) s_wt[tid >> 6] = inc;
    __syncthreads();
    if (tid == 0) {
        uint32_t run = 0;
        #pragma unroll
        for (int w = 0; w < 16; ++w) { uint32_t t = s_wt[w]; s_wt[w] = run; run += t; }
    }
    __syncthreads();
    uint32_t ex = s_wt[tid >> 6] + (inc - s);
    uint32_t e0 = ex, e1 = ex + a0, e2 = e1 + a1, e3 = e2 + a2;
    s_start[j0+0] = e0; s_start[j0+1] = e1; s_start[j0+2] = e2; s_start[j0+3] = e3;
    s_fill[j0+0] = 0u;  s_fill[j0+1] = 0u;  s_fill[j0+2] = 0u;  s_fill[j0+3] = 0u;
    __syncthreads();

    for (uint32_t i = tid; i < n; i += 1024) {
        uint32_t lo = gbin[base + i];
        unsigned long long pmv = __builtin_nontemporal_load(&gpm[base + i]);
        uint32_t slot = s_start[lo] + atomicAdd(&s_fill[lo], 1u);
        srt[base + slot] = pmv;
    }
    __threadfence_block();
    __syncthreads();

    uint32_t cs[4] = {a0, a1, a2, a3};
    uint32_t ss[4] = {e0, e1, e2, e3};
    #pragma unroll
    for (int t = 0; t < 4; ++t) {
        uint32_t c = cs[t];
        unsigned long long* arr = srt + base + ss[t];
        for (uint32_t x = 1; x < c; ++x) {
            unsigned long long v2 = arr[x];
            int y = (int)x - 1;
            while (y >= 0 && arr[y] > v2) { arr[y+1] = arr[y]; --y; }
            arr[y+1] = v2;
        }
        float sum = 0.0f;
        for (uint32_t x = 0; x < c; ++x)
            sum += __uint_as_float((uint32_t)arr[x]);
        size_t gbidx = (size_t)b * BPB + (size_t)(j0 + t);
        counts[gbidx] = c;
        lsum[gbidx]   = sum;
    }
}

// ---------------- last-resort fallback: direct atomics ---------------------
__global__ void hist_direct_kernel(const u32x4* __restrict__ img4,
                                   const u32x4* __restrict__ mask4,
                                   uint32_t* __restrict__ counts,
                                   float* __restrict__ lsum, int npix4) {
    int t = blockIdx.x * blockDim.x + threadIdx.x;
    if (t >= npix4) return;
    u32x4 a = img4[3 * t + 0];
    u32x4 b = img4[3 * t + 1];
    u32x4 c = img4[3 * t + 2];
    u32x4 m = mask4[t];
    uint32_t b0 = ((a.x >> 1) << 14) | ((a.y >> 1) << 7) | (a.z >> 1);
    uint32_t b1 = ((a.w >> 1) << 14) | ((b.x >> 1) << 7) | (b.y >> 1);
    uint32_t b2 = ((b.z >> 1) << 14) | ((b.w >> 1) << 7) | (c.x >> 1);
    uint32_t b3 = ((c.y >> 1) << 14) | ((c.z >> 1) << 7) | (c.w >> 1);
    atomicAdd(&counts[b0], 1u);
    atomicAdd(&counts[b1], 1u);
    atomicAdd(&counts[b2], 1u);
    atomicAdd(&counts[b3], 1u);
    unsafeAtomicAdd(&lsum[b0], __uint_as_float(m.x));
    unsafeAtomicAdd(&lsum[b1], __uint_as_float(m.y));
    unsafeAtomicAdd(&lsum[b2], __uint_as_float(m.z));
    unsafeAtomicAdd(&lsum[b3], __uint_as_float(m.w));
}

// ---------------- deterministic bin-space pipeline -------------------------
__global__ __launch_bounds__(256) void reduce_lf_kernel(
    const uint32_t* __restrict__ counts, const float* __restrict__ lsum,
    const float* __restrict__ full_in, const float* __restrict__ lines_in,
    double* __restrict__ part_lf, int nbin) {
    double sl = 0.0, sf = 0.0;
    for (int i = blockIdx.x * 256 + threadIdx.x; i < nbin; i += 256 * 256) {
        float f = (float)counts[i] + full_in[i] + 1.0f;
        float l = (lsum[i] + lines_in[i]) + 1e-10f;
        sl += (double)l;
        sf += (double)f;
    }
    for (int o = 32; o > 0; o >>= 1) {
        sl += __shfl_down(sl, o, 64);
        sf += __shfl_down(sf, o, 64);
    }
    __shared__ double s0[4], s1[4];
    int lane = threadIdx.x & 63, wid = threadIdx.x >> 6;
    if (lane == 0) { s0[wid] = sl; s1[wid] = sf; }
    __syncthreads();
    if (threadIdx.x == 0) {
        part_lf[blockIdx.x * 2 + 0] = s0[0] + s0[1] + s0[2] + s0[3];
        part_lf[blockIdx.x * 2 + 1] = s1[0] + s1[1] + s1[2] + s1[3];
    }
}

__global__ void final_lf_kernel(const double* __restrict__ part_lf,
                                double* __restrict__ accum) {
    if (threadIdx.x == 0 && blockIdx.x == 0) {
        double sl = 0.0, sf = 0.0;
        for (int i = 0; i < 256; ++i) { sl += part_lf[2*i]; sf += part_lf[2*i+1]; }
        accum[0] = sl;
        accum[1] = sf;
    }
}

__global__ __launch_bounds__(256) void logr_kernel(
    const uint32_t* __restrict__ counts, const float* __restrict__ lsum,
    const float* __restrict__ full_in, const float* __restrict__ lines_in,
    const double* __restrict__ accum, double* __restrict__ part_avg,
    float* __restrict__ logr, int nbin) {
    float Sl = (float)accum[0];
    float Sf = (float)accum[1];
    double acc = 0.0;
    for (int i = blockIdx.x * 256 + threadIdx.x; i < nbin; i += 256 * 256) {
        float f = (float)counts[i] + full_in[i] + 1.0f;
        float l = (lsum[i] + lines_in[i]) + 1e-10f;
        float ln = l / Sl;
        float fn = f / Sf;
        float lr = logf(ln / fn);
        logr[i] = lr;
        acc += (double)(ln * lr);
    }
    for (int o = 32; o > 0; o >>= 1) acc += __shfl_down(acc, o, 64);
    __shared__ double s[4];
    int lane = threadIdx.x & 63, wid = threadIdx.x >> 6;
    if (lane == 0) s[wid] = acc;
    __syncthreads();
    if (threadIdx.x == 0) part_avg[blockIdx.x] = s[0] + s[1] + s[2] + s[3];
}

__global__ void final_avg_kernel(const double* __restrict__ part_avg,
                                 double* __restrict__ accum) {
    if (threadIdx.x == 0 && blockIdx.x == 0) {
        double a = 0.0;
        for (int i = 0; i < 256; ++i) a += part_avg[i];
        accum[2] = a;
    }
}

__global__ void filt_kernel(const float* __restrict__ logr,
                            const double* __restrict__ accum,
                            uint8_t* __restrict__ filt, int nbin) {
    float avg = (float)accum[2];
    int i = blockIdx.x * blockDim.x + threadIdx.x;
    if (i < nbin) filt[i] = (logr[i] > avg) ? (uint8_t)1 : (uint8_t)0;
}

__global__ void out_kernel_img(const u32x4* __restrict__ img4,
                               const uint8_t* __restrict__ filt,
                               u32x4* __restrict__ out4, int npix4) {
    int t = blockIdx.x * blockDim.x + threadIdx.x;
    if (t >= npix4) return;
    u32x4 a = __builtin_nontemporal_load(&img4[3 * t + 0]);
    u32x4 b = __builtin_nontemporal_load(&img4[3 * t + 1]);
    u32x4 c = __builtin_nontemporal_load(&img4[3 * t + 2]);
    uint32_t b0 = ((a.x >> 1) << 14) | ((a.y >> 1) << 7) | (a.z >> 1);
    uint32_t b1 = ((a.w >> 1) << 14) | ((b.x >> 1) << 7) | (b.y >> 1);
    uint32_t b2 = ((b.z >> 1) << 14) | ((b.w >> 1) << 7) | (c.x >> 1);
    uint32_t b3 = ((c.y >> 1) << 14) | ((c.z >> 1) << 7) | (c.w >> 1);
    u32x4 o = {filt[b0] ? 1u : 0u, filt[b1] ? 1u : 0u,
               filt[b2] ? 1u : 0u, filt[b3] ? 1u : 0u};
    __builtin_nontemporal_store(o, &out4[t]);
}

extern "C" void kernel_launch(void* const* d_in, const int* in_sizes, int n_in,
                              void* d_out, int out_size, void* d_ws, size_t ws_size,
                              hipStream_t stream) {
    const int*   img      = (const int*)d_in[0];
    const float* mask     = (const float*)d_in[1];
    const float* full_in  = (const float*)d_in[2];
    const float* lines_in = (const float*)d_in[3];

    const int npix  = in_sizes[1];     // 4096*4096
    const int nbin  = in_sizes[2];     // 128^3
    const int npix4 = npix / 4;

    char* ws = (char*)d_ws;
    const size_t off_cursor = 64;
    const size_t off_plf    = off_cursor + 4ull * NBKT;
    const size_t off_pavg   = off_plf + 256ull * 2 * 8;
    const size_t off_cnt2   = off_pavg + 256ull * 8;
    const size_t off_hdrend = (off_cnt2 + 4ull * NBKT * NSUB + 255ull) & ~255ull;
    const size_t off_counts = off_hdrend;
    const size_t off_lsum   = off_counts + 4ull * nbin;
    const size_t off_logr   = off_lsum + 4ull * nbin;
    const size_t off_filt   = off_logr + 4ull * nbin;
    const size_t off_gbin   = (off_filt + (size_t)nbin + 255ull) & ~255ull;
    const size_t off_gpm    = (off_gbin + 2ull * NBKT * CAP + 255ull) & ~255ull;
    const size_t off_union  = off_gpm + 8ull * NBKT * CAP;
    // mid tier: srt at off_union (8B * NBKT * CAP)
    const size_t need_mid   = off_union + 8ull * NBKT * CAP;
    // new tier: gb2 + gpm2 at off_union
    const size_t off_gb2    = off_union;
    const size_t off_gpm2   = (off_gb2 + 2ull * NBKT * NSUB * SUBCAP + 255ull) & ~255ull;
    const size_t need_new   = off_gpm2 + 8ull * NBKT * NSUB * SUBCAP;

    double*   accum  = (double*)ws;
    uint32_t* cursor = (uint32_t*)(ws + off_cursor);
    double*   plf    = (double*)(ws + off_plf);
    double*   pavg   = (double*)(ws + off_pavg);
    uint32_t* cnt2   = (uint32_t*)(ws + off_cnt2);
    uint32_t* counts = (uint32_t*)(ws + off_counts);
    float*    lsum   = (float*)(ws + off_lsum);
    float*    logr   = (float*)(ws + off_logr);
    uint8_t*  filt   = (uint8_t*)(ws + off_filt);
    unsigned short*     gbin = (unsigned short*)(ws + off_gbin);
    unsigned long long* gpm  = (unsigned long long*)(ws + off_gpm);
    unsigned long long* srt  = (unsigned long long*)(ws + off_union);
    unsigned short*     gb2  = (unsigned short*)(ws + off_gb2);
    unsigned long long* gpm2 = (unsigned long long*)(ws + off_gpm2);

    const bool shape_ok = (nbin == NBKT * BPB) && (npix % (P1_PIXG * 4) == 0);
    const bool tier_new = shape_ok && ws_size >= need_new;
    const bool tier_mid = shape_ok && ws_size >= need_mid;
    const int BLK = 256;

    if (tier_new) {
        hipMemsetAsync(ws, 0, off_hdrend, stream);
        p1_scatter_det<<<npix / (P1_PIXG * 4), P1_BLK, 0, stream>>>(
            (const u32x4*)img, (const u32x4*)mask, cursor, gbin, gpm);
        p15_subpart<<<NBKT, 1024, 0, stream>>>(gbin, gpm, cursor, gb2, gpm2, cnt2);
        p2_binhist<<<NBKT * NSUB, 512, 0, stream>>>(gb2, gpm2, cnt2, counts, lsum);
    } else if (tier_mid) {
        hipMemsetAsync(ws, 0, off_hdrend, stream);
        p1_scatter_det<<<npix / (P1_PIXG * 4), P1_BLK, 0, stream>>>(
            (const u32x4*)img, (const u32x4*)mask, cursor, gbin, gpm);
        p2_sort_hist<<<NBKT, 1024, 0, stream>>>(gbin, gpm, cursor, srt, counts, lsum);
    } else {
        hipMemsetAsync(ws, 0, off_logr, stream);
        hist_direct_kernel<<<(npix4 + BLK - 1) / BLK, BLK, 0, stream>>>(
            (const u32x4*)img, (const u32x4*)mask, counts, lsum, npix4);
    }

    reduce_lf_kernel<<<256, 256, 0, stream>>>(counts, lsum, full_in, lines_in, plf, nbin);
    final_lf_kernel<<<1, 64, 0, stream>>>(plf, accum);
    logr_kernel<<<256, 256, 0, stream>>>(counts, lsum, full_in, lines_in,
                                         accum, pavg, logr, nbin);
    final_avg_kernel<<<1, 64, 0, stream>>>(pavg, accum);
    filt_kernel<<<(nbin + BLK - 1) / BLK, BLK, 0, stream>>>(logr, accum, filt, nbin);
    out_kernel_img<<<(npix4 + BLK - 1) / BLK, BLK, 0, stream>>>(
        (const u32x4*)img, filt, (u32x4*)d_out, npix4);
}